// Round 9
// baseline (1195.020 us; speedup 1.0000x reference)
//
#include <hip/hip_runtime.h>
#include <hip/hip_bf16.h>

#define BATCH 512
#define NNODE 131072
#define NEDGE 131072
#define NLAYER 4
#define SCAN_BLK 1024
#define SCAN_NBLK (NNODE / SCAN_BLK)   // 128
#define PCAP (8 * NEDGE)               // per-pair entry capacity (expected ~4N)

// Per-layer CSR (application order: layer 0 = edges3 ... layer 3 = edges0)
__device__ int g_counts[NLAYER][NNODE];
__device__ int g_offs[NLAYER][NNODE];
__device__ int g_cursor[NLAYER][NNODE];
__device__ int g_srcl[NLAYER][NEDGE];
__device__ int g_bsums[NLAYER][SCAN_NBLK];

// Pair-combined CSR: pair0 = (I+A3)(I+A2), pair1 = (I+A1)(I+A0). Identity included.
__device__ int p_cnt[2][NNODE];
__device__ int p_offs[2][NNODE];
__device__ int p_srcl[2][PCAP];
__device__ int p_bsums[2][SCAN_NBLK];

typedef unsigned int uivec4 __attribute__((ext_vector_type(4)));
typedef float fvec4 __attribute__((ext_vector_type(4)));

__device__ __forceinline__ void nt_store_u4(uint4* p, uint4 v) {
    uivec4 w = {v.x, v.y, v.z, v.w};
    __builtin_nontemporal_store(w, reinterpret_cast<uivec4*>(p));
}

__device__ __forceinline__ void nt_store_f4(float4* p, float4 v) {
    fvec4 w = {v.x, v.y, v.z, v.w};
    __builtin_nontemporal_store(w, reinterpret_cast<fvec4*>(p));
}

// ---- per-layer CSR build ----
__global__ void zero_counts_k() {
    int i = blockIdx.x * blockDim.x + threadIdx.x;
    ((int*)g_counts)[i] = 0;
}

__global__ void hist_k(const int* __restrict__ p0, const int* __restrict__ p1,
                       const int* __restrict__ p2, const int* __restrict__ p3) {
    int i = blockIdx.x * blockDim.x + threadIdx.x;
    int layer = i >> 17;
    int e = i & (NEDGE - 1);
    const int* eg = layer == 0 ? p0 : layer == 1 ? p1 : layer == 2 ? p2 : p3;
    atomicAdd(&g_counts[layer][eg[NEDGE + e]], 1);
}

__global__ void scan_block_k() {
    __shared__ int sh[SCAN_BLK];
    int layer = blockIdx.x / SCAN_NBLK;
    int blk = blockIdx.x % SCAN_NBLK;
    int t = threadIdx.x;
    int i = blk * SCAN_BLK + t;
    int own = g_counts[layer][i];
    sh[t] = own;
    __syncthreads();
    for (int off = 1; off < SCAN_BLK; off <<= 1) {
        int v = (t >= off) ? sh[t - off] : 0;
        __syncthreads();
        sh[t] += v;
        __syncthreads();
    }
    g_offs[layer][i] = sh[t] - own;
    if (t == SCAN_BLK - 1) g_bsums[layer][blk] = sh[t];
}

__global__ void scan_bsums_k() {
    __shared__ int sh[SCAN_NBLK];
    int layer = blockIdx.x;
    int t = threadIdx.x;
    int own = g_bsums[layer][t];
    sh[t] = own;
    __syncthreads();
    for (int off = 1; off < SCAN_NBLK; off <<= 1) {
        int v = (t >= off) ? sh[t - off] : 0;
        __syncthreads();
        sh[t] += v;
        __syncthreads();
    }
    g_bsums[layer][t] = sh[t] - own;
}

__global__ void scan_add_k() {
    int layer = blockIdx.x / SCAN_NBLK;
    int blk = blockIdx.x % SCAN_NBLK;
    int i = blk * SCAN_BLK + threadIdx.x;
    int o = g_offs[layer][i] + g_bsums[layer][blk];
    g_offs[layer][i] = o;
    g_cursor[layer][i] = o;
}

__global__ void fill_k(const int* __restrict__ p0, const int* __restrict__ p1,
                       const int* __restrict__ p2, const int* __restrict__ p3) {
    int i = blockIdx.x * blockDim.x + threadIdx.x;
    int layer = i >> 17;
    int e = i & (NEDGE - 1);
    const int* eg = layer == 0 ? p0 : layer == 1 ? p1 : layer == 2 ? p2 : p3;
    int s = eg[e];
    int d = eg[NEDGE + e];
    int p = atomicAdd(&g_cursor[layer][d], 1);
    g_srcl[layer][p] = s;
}

// ---- pair combine: P = (I+A_U)(I+A_V), col(d) = Ucol(d) + sum_{s in Vcol(d)} Ucol(s)
__global__ void count_pair_k() {
    int i = blockIdx.x * blockDim.x + threadIdx.x;  // 0..2N
    int pr = i >> 17;
    int d = i & (NNODE - 1);
    int U = pr * 2, V = pr * 2 + 1;
    int c = 1 + g_counts[U][d];
    int vb = g_offs[V][d], vd = g_counts[V][d];
    for (int j = 0; j < vd; ++j) {
        int s = g_srcl[V][vb + j];
        c += 1 + g_counts[U][s];
    }
    p_cnt[pr][d] = c;
}

__global__ void pscan_block_k() {
    __shared__ int sh[SCAN_BLK];
    int pr = blockIdx.x / SCAN_NBLK;
    int blk = blockIdx.x % SCAN_NBLK;
    int t = threadIdx.x;
    int i = blk * SCAN_BLK + t;
    int own = p_cnt[pr][i];
    sh[t] = own;
    __syncthreads();
    for (int off = 1; off < SCAN_BLK; off <<= 1) {
        int v = (t >= off) ? sh[t - off] : 0;
        __syncthreads();
        sh[t] += v;
        __syncthreads();
    }
    p_offs[pr][i] = sh[t] - own;
    if (t == SCAN_BLK - 1) p_bsums[pr][blk] = sh[t];
}

__global__ void pscan_bsums_k() {
    __shared__ int sh[SCAN_NBLK];
    int pr = blockIdx.x;
    int t = threadIdx.x;
    int own = p_bsums[pr][t];
    sh[t] = own;
    __syncthreads();
    for (int off = 1; off < SCAN_NBLK; off <<= 1) {
        int v = (t >= off) ? sh[t - off] : 0;
        __syncthreads();
        sh[t] += v;
        __syncthreads();
    }
    p_bsums[pr][t] = sh[t] - own;
}

__global__ void pscan_add_k() {
    int pr = blockIdx.x / SCAN_NBLK;
    int blk = blockIdx.x % SCAN_NBLK;
    int i = blk * SCAN_BLK + threadIdx.x;
    p_offs[pr][i] += p_bsums[pr][blk];
}

__global__ void fill_pair_k() {
    int i = blockIdx.x * blockDim.x + threadIdx.x;  // 0..2N
    int pr = i >> 17;
    int d = i & (NNODE - 1);
    int U = pr * 2, V = pr * 2 + 1;
    int p = p_offs[pr][d];
    int* buf = p_srcl[pr];
    buf[p++] = d;
    int ub = g_offs[U][d], ud = g_counts[U][d];
    for (int j = 0; j < ud; ++j) buf[p++] = g_srcl[U][ub + j];
    int vb = g_offs[V][d], vd = g_counts[V][d];
    for (int j = 0; j < vd; ++j) {
        int s = g_srcl[V][vb + j];
        buf[p++] = s;
        int sb = g_offs[U][s], sd = g_counts[U][s];
        for (int k = 0; k < sd; ++k) buf[p++] = g_srcl[U][sb + k];
    }
}

// ---- transpose with bf16 output: x (B,N) f32 -> out (N,B) bf16. 64x64 tiles,
// blockDim (16,16), 4 rows/thread. Cached stores (sweep0 reads this next).
__global__ void transpose_bf_k(const float* __restrict__ in, unsigned short* __restrict__ out) {
    __shared__ float tile[64][65];
    int c0 = blockIdx.x * 64;   // N dim
    int r0 = blockIdx.y * 64;   // B dim
    int tx = threadIdx.x;
    int ty = threadIdx.y;
    float4 v[4];
#pragma unroll
    for (int i = 0; i < 4; ++i)
        v[i] = *reinterpret_cast<const float4*>(&in[(size_t)(r0 + ty + 16 * i) * NNODE + c0 + 4 * tx]);
#pragma unroll
    for (int i = 0; i < 4; ++i) {
        tile[ty + 16 * i][4 * tx + 0] = v[i].x;
        tile[ty + 16 * i][4 * tx + 1] = v[i].y;
        tile[ty + 16 * i][4 * tx + 2] = v[i].z;
        tile[ty + 16 * i][4 * tx + 3] = v[i].w;
    }
    __syncthreads();
#pragma unroll
    for (int i = 0; i < 4; ++i) {
        int n = c0 + ty + 16 * i;
        ushort4 w;
        __hip_bfloat16 h0 = __float2bfloat16(tile[4 * tx + 0][ty + 16 * i]);
        __hip_bfloat16 h1 = __float2bfloat16(tile[4 * tx + 1][ty + 16 * i]);
        __hip_bfloat16 h2 = __float2bfloat16(tile[4 * tx + 2][ty + 16 * i]);
        __hip_bfloat16 h3 = __float2bfloat16(tile[4 * tx + 3][ty + 16 * i]);
        w.x = *reinterpret_cast<unsigned short*>(&h0);
        w.y = *reinterpret_cast<unsigned short*>(&h1);
        w.z = *reinterpret_cast<unsigned short*>(&h2);
        w.w = *reinterpret_cast<unsigned short*>(&h3);
        *reinterpret_cast<ushort4*>(&out[(size_t)n * BATCH + r0 + 4 * tx]) = w;
    }
}

// bf16 unpack-accumulate: uint4 = 8 bf16 -> 8 f32 adds (bf16->f32 is a shift)
__device__ __forceinline__ void gacc8(float* a, uint4 v) {
    a[0] += __uint_as_float(v.x << 16);
    a[1] += __uint_as_float(v.x & 0xffff0000u);
    a[2] += __uint_as_float(v.y << 16);
    a[3] += __uint_as_float(v.y & 0xffff0000u);
    a[4] += __uint_as_float(v.z << 16);
    a[5] += __uint_as_float(v.z & 0xffff0000u);
    a[6] += __uint_as_float(v.w << 16);
    a[7] += __uint_as_float(v.w & 0xffff0000u);
}

__device__ __forceinline__ unsigned pack2(float lo, float hi) {
    __hip_bfloat16 l = __float2bfloat16(lo);
    __hip_bfloat16 h = __float2bfloat16(hi);
    return (unsigned)*reinterpret_cast<unsigned short*>(&l) |
           ((unsigned)*reinterpret_cast<unsigned short*>(&h) << 16);
}

// Shared gather body: cur is (N,B) bf16 as uint4 (64 per node). One lane load
// covers 8 batch elems; whole column = 1 wave-load. x4 unroll, 4 acc sets.
__device__ __forceinline__ void gather_body_bf(const uint4* __restrict__ cur,
                                               const int* __restrict__ sl, int deg, int q,
                                               float acc[8]) {
    float A[8] = {0, 0, 0, 0, 0, 0, 0, 0};
    float B_[8] = {0, 0, 0, 0, 0, 0, 0, 0};
    float C_[8] = {0, 0, 0, 0, 0, 0, 0, 0};
    float D_[8] = {0, 0, 0, 0, 0, 0, 0, 0};
    int j = 0;
    for (; j + 4 <= deg; j += 4) {
        uint4 v0 = cur[(size_t)sl[j + 0] * 64 + q];
        uint4 v1 = cur[(size_t)sl[j + 1] * 64 + q];
        uint4 v2 = cur[(size_t)sl[j + 2] * 64 + q];
        uint4 v3 = cur[(size_t)sl[j + 3] * 64 + q];
        gacc8(A, v0);
        gacc8(B_, v1);
        gacc8(C_, v2);
        gacc8(D_, v3);
    }
    for (; j < deg; ++j) {
        uint4 v = cur[(size_t)sl[j] * 64 + q];
        gacc8(A, v);
    }
#pragma unroll
    for (int k = 0; k < 8; ++k) acc[k] = A[k] + B_[k] + C_[k] + D_[k];
}

// ---- pair gather (bf16 -> bf16): 8 nodes per 512-thread block, one wave/node.
// NT store: keep the read-only source buffer L3-resident.
__global__ void gather_p_k(const uint4* __restrict__ cur, uint4* __restrict__ out,
                           int pr) {
    int t = threadIdx.x;
    int n = blockIdx.x * 8 + (t >> 6);
    int q = t & 63;
    int beg = p_offs[pr][n];
    int deg = p_cnt[pr][n];
    float acc[8];
    gather_body_bf(cur, &p_srcl[pr][beg], deg, q, acc);
    uint4 w;
    w.x = pack2(acc[0], acc[1]);
    w.y = pack2(acc[2], acc[3]);
    w.z = pack2(acc[4], acc[5]);
    w.w = pack2(acc[6], acc[7]);
    nt_store_u4(&out[(size_t)n * 64 + q], w);
}

// ---- last pair gather (bf16 -> f32) fused with transpose-back.
// 512 threads, 8 nodes/block (one wave/node). cur (N,B) bf16 -> out (B,N) f32.
// NT stores on d_out (never re-read).
__global__ void __launch_bounds__(512) gather_tr_p_k(const uint4* __restrict__ cur,
                                                     float* __restrict__ out, int pr) {
    __shared__ float lds[8][520];
    int t = threadIdx.x;
    int n0 = blockIdx.x * 8;
    int nn = t >> 6;            // 0..7
    int q = t & 63;
    int n = n0 + nn;
    int beg = p_offs[pr][n];
    int deg = p_cnt[pr][n];
    float acc[8];
    gather_body_bf(cur, &p_srcl[pr][beg], deg, q, acc);
    // lds[nn][b] = value for batch b of node nn (b = 8q+k)
    float4* lrow = reinterpret_cast<float4*>(&lds[nn][8 * q]);
    lrow[0] = make_float4(acc[0], acc[1], acc[2], acc[3]);
    lrow[1] = make_float4(acc[4], acc[5], acc[6], acc[7]);
    __syncthreads();
    int b = t;                  // 0..511
    float4 w0, w1;
    w0.x = lds[0][b]; w0.y = lds[1][b]; w0.z = lds[2][b]; w0.w = lds[3][b];
    w1.x = lds[4][b]; w1.y = lds[5][b]; w1.z = lds[6][b]; w1.w = lds[7][b];
    float4* orow = reinterpret_cast<float4*>(&out[(size_t)b * NNODE + n0]);
    nt_store_f4(&orow[0], w0);
    nt_store_f4(&orow[1], w1);
}

extern "C" void kernel_launch(void* const* d_in, const int* in_sizes, int n_in,
                              void* d_out, int out_size, void* d_ws, size_t ws_size,
                              hipStream_t stream) {
    const float* x = (const float*)d_in[0];
    // Application order: edges3 (layer 0) ... edges0 (layer 3)
    const int* p0 = (const int*)d_in[4];
    const int* p1 = (const int*)d_in[3];
    const int* p2 = (const int*)d_in[2];
    const int* p3 = (const int*)d_in[1];

    // Two bf16 (N,B) buffers in d_ws: 128 MB each
    unsigned short* WS0 = (unsigned short*)d_ws;
    unsigned short* WS1 = WS0 + (size_t)NNODE * BATCH;
    float* OUT = (float*)d_out;

    // Per-layer CSR
    zero_counts_k<<<NLAYER * NNODE / 1024, 1024, 0, stream>>>();
    hist_k<<<NLAYER * NEDGE / 1024, 1024, 0, stream>>>(p0, p1, p2, p3);
    scan_block_k<<<NLAYER * SCAN_NBLK, SCAN_BLK, 0, stream>>>();
    scan_bsums_k<<<NLAYER, SCAN_NBLK, 0, stream>>>();
    scan_add_k<<<NLAYER * SCAN_NBLK, SCAN_BLK, 0, stream>>>();
    fill_k<<<NLAYER * NEDGE / 1024, 1024, 0, stream>>>(p0, p1, p2, p3);

    // Pair-combined CSR (2 pairs)
    count_pair_k<<<2 * NNODE / 1024, 1024, 0, stream>>>();
    pscan_block_k<<<2 * SCAN_NBLK, SCAN_BLK, 0, stream>>>();
    pscan_bsums_k<<<2, SCAN_NBLK, 0, stream>>>();
    pscan_add_k<<<2 * SCAN_NBLK, SCAN_BLK, 0, stream>>>();
    fill_pair_k<<<2 * NNODE / 256, 256, 0, stream>>>();

    // x (B,N) f32 -> WS0 (N,B) bf16 (cached stores: sweep0 reads it next)
    transpose_bf_k<<<dim3(NNODE / 64, BATCH / 64), dim3(16, 16), 0, stream>>>(x, WS0);

    // sweep 0 (pair 0): WS0 -> WS1 (bf16, NT)
    gather_p_k<<<NNODE / 8, 512, 0, stream>>>((const uint4*)WS0, (uint4*)WS1, 0);
    // sweep 1 (pair 1) fused with transpose-back: WS1 (N,B) bf16 -> d_out (B,N) f32 (NT)
    gather_tr_p_k<<<NNODE / 8, 512, 0, stream>>>((const uint4*)WS1, OUT, 1);
}

// Round 10
// 506.092 us; speedup vs baseline: 2.3613x; 2.3613x over previous
//
#include <hip/hip_runtime.h>
#include <hip/hip_bf16.h>

#define BATCH 512
#define NNODE 131072
#define NEDGE 131072
#define NLAYER 4
#define SCAN_BLK 1024
#define SCAN_NBLK (NNODE / SCAN_BLK)   // 128
#define PCAP (8 * NEDGE)               // per-pair entry capacity (expected ~4N)

// Per-layer CSR (application order: layer 0 = edges3 ... layer 3 = edges0)
__device__ int g_counts[NLAYER][NNODE];
__device__ int g_offs[NLAYER][NNODE];
__device__ int g_cursor[NLAYER][NNODE];
__device__ int g_srcl[NLAYER][NEDGE];
__device__ int g_bsums[NLAYER][SCAN_NBLK];

// Pair-combined CSR: pair0 = (I+A3)(I+A2), pair1 = (I+A1)(I+A0). Identity included.
__device__ int p_cnt[2][NNODE];
__device__ int p_offs[2][NNODE];
__device__ int p_srcl[2][PCAP];
__device__ int p_bsums[2][SCAN_NBLK];

typedef unsigned int uivec4 __attribute__((ext_vector_type(4)));
typedef float fvec4 __attribute__((ext_vector_type(4)));

__device__ __forceinline__ void nt_store_u4(uint4* p, uint4 v) {
    uivec4 w = {v.x, v.y, v.z, v.w};
    __builtin_nontemporal_store(w, reinterpret_cast<uivec4*>(p));
}

__device__ __forceinline__ void nt_store_f4(float* p, float4 v) {
    fvec4 w = {v.x, v.y, v.z, v.w};
    __builtin_nontemporal_store(w, reinterpret_cast<fvec4*>(p));
}

// ---- per-layer CSR build ----
__global__ void zero_counts_k() {
    int i = blockIdx.x * blockDim.x + threadIdx.x;
    ((int*)g_counts)[i] = 0;
}

__global__ void hist_k(const int* __restrict__ p0, const int* __restrict__ p1,
                       const int* __restrict__ p2, const int* __restrict__ p3) {
    int i = blockIdx.x * blockDim.x + threadIdx.x;
    int layer = i >> 17;
    int e = i & (NEDGE - 1);
    const int* eg = layer == 0 ? p0 : layer == 1 ? p1 : layer == 2 ? p2 : p3;
    atomicAdd(&g_counts[layer][eg[NEDGE + e]], 1);
}

__global__ void scan_block_k() {
    __shared__ int sh[SCAN_BLK];
    int layer = blockIdx.x / SCAN_NBLK;
    int blk = blockIdx.x % SCAN_NBLK;
    int t = threadIdx.x;
    int i = blk * SCAN_BLK + t;
    int own = g_counts[layer][i];
    sh[t] = own;
    __syncthreads();
    for (int off = 1; off < SCAN_BLK; off <<= 1) {
        int v = (t >= off) ? sh[t - off] : 0;
        __syncthreads();
        sh[t] += v;
        __syncthreads();
    }
    g_offs[layer][i] = sh[t] - own;
    if (t == SCAN_BLK - 1) g_bsums[layer][blk] = sh[t];
}

__global__ void scan_bsums_k() {
    __shared__ int sh[SCAN_NBLK];
    int layer = blockIdx.x;
    int t = threadIdx.x;
    int own = g_bsums[layer][t];
    sh[t] = own;
    __syncthreads();
    for (int off = 1; off < SCAN_NBLK; off <<= 1) {
        int v = (t >= off) ? sh[t - off] : 0;
        __syncthreads();
        sh[t] += v;
        __syncthreads();
    }
    g_bsums[layer][t] = sh[t] - own;
}

__global__ void scan_add_k() {
    int layer = blockIdx.x / SCAN_NBLK;
    int blk = blockIdx.x % SCAN_NBLK;
    int i = blk * SCAN_BLK + threadIdx.x;
    int o = g_offs[layer][i] + g_bsums[layer][blk];
    g_offs[layer][i] = o;
    g_cursor[layer][i] = o;
}

__global__ void fill_k(const int* __restrict__ p0, const int* __restrict__ p1,
                       const int* __restrict__ p2, const int* __restrict__ p3) {
    int i = blockIdx.x * blockDim.x + threadIdx.x;
    int layer = i >> 17;
    int e = i & (NEDGE - 1);
    const int* eg = layer == 0 ? p0 : layer == 1 ? p1 : layer == 2 ? p2 : p3;
    int s = eg[e];
    int d = eg[NEDGE + e];
    int p = atomicAdd(&g_cursor[layer][d], 1);
    g_srcl[layer][p] = s;
}

// ---- pair combine: P = (I+A_U)(I+A_V), col(d) = Ucol(d) + sum_{s in Vcol(d)} Ucol(s)
__global__ void count_pair_k() {
    int i = blockIdx.x * blockDim.x + threadIdx.x;  // 0..2N
    int pr = i >> 17;
    int d = i & (NNODE - 1);
    int U = pr * 2, V = pr * 2 + 1;
    int c = 1 + g_counts[U][d];
    int vb = g_offs[V][d], vd = g_counts[V][d];
    for (int j = 0; j < vd; ++j) {
        int s = g_srcl[V][vb + j];
        c += 1 + g_counts[U][s];
    }
    p_cnt[pr][d] = c;
}

__global__ void pscan_block_k() {
    __shared__ int sh[SCAN_BLK];
    int pr = blockIdx.x / SCAN_NBLK;
    int blk = blockIdx.x % SCAN_NBLK;
    int t = threadIdx.x;
    int i = blk * SCAN_BLK + t;
    int own = p_cnt[pr][i];
    sh[t] = own;
    __syncthreads();
    for (int off = 1; off < SCAN_BLK; off <<= 1) {
        int v = (t >= off) ? sh[t - off] : 0;
        __syncthreads();
        sh[t] += v;
        __syncthreads();
    }
    p_offs[pr][i] = sh[t] - own;
    if (t == SCAN_BLK - 1) p_bsums[pr][blk] = sh[t];
}

__global__ void pscan_bsums_k() {
    __shared__ int sh[SCAN_NBLK];
    int pr = blockIdx.x;
    int t = threadIdx.x;
    int own = p_bsums[pr][t];
    sh[t] = own;
    __syncthreads();
    for (int off = 1; off < SCAN_NBLK; off <<= 1) {
        int v = (t >= off) ? sh[t - off] : 0;
        __syncthreads();
        sh[t] += v;
        __syncthreads();
    }
    p_bsums[pr][t] = sh[t] - own;
}

__global__ void pscan_add_k() {
    int pr = blockIdx.x / SCAN_NBLK;
    int blk = blockIdx.x % SCAN_NBLK;
    int i = blk * SCAN_BLK + threadIdx.x;
    p_offs[pr][i] += p_bsums[pr][blk];
}

__global__ void fill_pair_k() {
    int i = blockIdx.x * blockDim.x + threadIdx.x;  // 0..2N
    int pr = i >> 17;
    int d = i & (NNODE - 1);
    int U = pr * 2, V = pr * 2 + 1;
    int p = p_offs[pr][d];
    int* buf = p_srcl[pr];
    buf[p++] = d;
    int ub = g_offs[U][d], ud = g_counts[U][d];
    for (int j = 0; j < ud; ++j) buf[p++] = g_srcl[U][ub + j];
    int vb = g_offs[V][d], vd = g_counts[V][d];
    for (int j = 0; j < vd; ++j) {
        int s = g_srcl[V][vb + j];
        buf[p++] = s;
        int sb = g_offs[U][s], sd = g_counts[U][s];
        for (int k = 0; k < sd; ++k) buf[p++] = g_srcl[U][sb + k];
    }
}

// ---- transpose with bf16 output: x (B,N) f32 -> out (N,B) bf16. 64x64 tiles,
// blockDim (16,16), 4 rows/thread. Cached stores (sweep0 reads this next).
__global__ void transpose_bf_k(const float* __restrict__ in, unsigned short* __restrict__ out) {
    __shared__ float tile[64][65];
    int c0 = blockIdx.x * 64;   // N dim
    int r0 = blockIdx.y * 64;   // B dim
    int tx = threadIdx.x;
    int ty = threadIdx.y;
    float4 v[4];
#pragma unroll
    for (int i = 0; i < 4; ++i)
        v[i] = *reinterpret_cast<const float4*>(&in[(size_t)(r0 + ty + 16 * i) * NNODE + c0 + 4 * tx]);
#pragma unroll
    for (int i = 0; i < 4; ++i) {
        tile[ty + 16 * i][4 * tx + 0] = v[i].x;
        tile[ty + 16 * i][4 * tx + 1] = v[i].y;
        tile[ty + 16 * i][4 * tx + 2] = v[i].z;
        tile[ty + 16 * i][4 * tx + 3] = v[i].w;
    }
    __syncthreads();
#pragma unroll
    for (int i = 0; i < 4; ++i) {
        int n = c0 + ty + 16 * i;
        ushort4 w;
        __hip_bfloat16 h0 = __float2bfloat16(tile[4 * tx + 0][ty + 16 * i]);
        __hip_bfloat16 h1 = __float2bfloat16(tile[4 * tx + 1][ty + 16 * i]);
        __hip_bfloat16 h2 = __float2bfloat16(tile[4 * tx + 2][ty + 16 * i]);
        __hip_bfloat16 h3 = __float2bfloat16(tile[4 * tx + 3][ty + 16 * i]);
        w.x = *reinterpret_cast<unsigned short*>(&h0);
        w.y = *reinterpret_cast<unsigned short*>(&h1);
        w.z = *reinterpret_cast<unsigned short*>(&h2);
        w.w = *reinterpret_cast<unsigned short*>(&h3);
        *reinterpret_cast<ushort4*>(&out[(size_t)n * BATCH + r0 + 4 * tx]) = w;
    }
}

// bf16 unpack-accumulate: uint4 = 8 bf16 -> 8 f32 adds (bf16->f32 is a shift)
__device__ __forceinline__ void gacc8(float* a, uint4 v) {
    a[0] += __uint_as_float(v.x << 16);
    a[1] += __uint_as_float(v.x & 0xffff0000u);
    a[2] += __uint_as_float(v.y << 16);
    a[3] += __uint_as_float(v.y & 0xffff0000u);
    a[4] += __uint_as_float(v.z << 16);
    a[5] += __uint_as_float(v.z & 0xffff0000u);
    a[6] += __uint_as_float(v.w << 16);
    a[7] += __uint_as_float(v.w & 0xffff0000u);
}

__device__ __forceinline__ unsigned pack2(float lo, float hi) {
    __hip_bfloat16 l = __float2bfloat16(lo);
    __hip_bfloat16 h = __float2bfloat16(hi);
    return (unsigned)*reinterpret_cast<unsigned short*>(&l) |
           ((unsigned)*reinterpret_cast<unsigned short*>(&h) << 16);
}

// Shared gather body: cur is (N,B) bf16 as uint4 (64 per node). One lane load
// covers 8 batch elems; whole column = 1 wave-load. x4 unroll, 4 acc sets.
__device__ __forceinline__ void gather_body_bf(const uint4* __restrict__ cur,
                                               const int* __restrict__ sl, int deg, int q,
                                               float acc[8]) {
    float A[8] = {0, 0, 0, 0, 0, 0, 0, 0};
    float B_[8] = {0, 0, 0, 0, 0, 0, 0, 0};
    float C_[8] = {0, 0, 0, 0, 0, 0, 0, 0};
    float D_[8] = {0, 0, 0, 0, 0, 0, 0, 0};
    int j = 0;
    for (; j + 4 <= deg; j += 4) {
        uint4 v0 = cur[(size_t)sl[j + 0] * 64 + q];
        uint4 v1 = cur[(size_t)sl[j + 1] * 64 + q];
        uint4 v2 = cur[(size_t)sl[j + 2] * 64 + q];
        uint4 v3 = cur[(size_t)sl[j + 3] * 64 + q];
        gacc8(A, v0);
        gacc8(B_, v1);
        gacc8(C_, v2);
        gacc8(D_, v3);
    }
    for (; j < deg; ++j) {
        uint4 v = cur[(size_t)sl[j] * 64 + q];
        gacc8(A, v);
    }
#pragma unroll
    for (int k = 0; k < 8; ++k) acc[k] = A[k] + B_[k] + C_[k] + D_[k];
}

// ---- pair gather (bf16 -> bf16): 8 nodes per 512-thread block, one wave/node.
// NT store is full-line here (wave writes 1 KB contiguous): keeps source L3-resident.
__global__ void gather_p_k(const uint4* __restrict__ cur, uint4* __restrict__ out,
                           int pr) {
    int t = threadIdx.x;
    int n = blockIdx.x * 8 + (t >> 6);
    int q = t & 63;
    int beg = p_offs[pr][n];
    int deg = p_cnt[pr][n];
    float acc[8];
    gather_body_bf(cur, &p_srcl[pr][beg], deg, q, acc);
    uint4 w;
    w.x = pack2(acc[0], acc[1]);
    w.y = pack2(acc[2], acc[3]);
    w.z = pack2(acc[4], acc[5]);
    w.w = pack2(acc[6], acc[7]);
    nt_store_u4(&out[(size_t)n * 64 + q], w);
}

// ---- last pair gather (bf16 -> f32) fused with transpose-back.
// 1024 threads, 16 nodes/block (one wave per node). cur (N,B) bf16 -> out (B,N) f32.
// Write phase: 4 consecutive lanes cover one row's 16 floats = one full 64B line
// per wave instruction -> NT stores without partial-line amplification.
__global__ void __launch_bounds__(1024) gather_tr_p_k(const uint4* __restrict__ cur,
                                                      float* __restrict__ out, int pr) {
    __shared__ float lds[16][520];
    int t = threadIdx.x;
    int n0 = blockIdx.x * 16;
    int nn = t >> 6;            // 0..15 (wave id = node)
    int q = t & 63;
    int n = n0 + nn;
    int beg = p_offs[pr][n];
    int deg = p_cnt[pr][n];
    float acc[8];
    gather_body_bf(cur, &p_srcl[pr][beg], deg, q, acc);
    // lds[nn][b] = value for batch b of node nn (b = 8q+k)
    float4* lrow = reinterpret_cast<float4*>(&lds[nn][8 * q]);
    lrow[0] = make_float4(acc[0], acc[1], acc[2], acc[3]);
    lrow[1] = make_float4(acc[4], acc[5], acc[6], acc[7]);
    __syncthreads();
    int c = t & 3;              // chunk within row (4 floats)
    int rb = t >> 2;            // 0..255
#pragma unroll
    for (int iter = 0; iter < 2; ++iter) {
        int b = iter * 256 + rb;
        float4 w;
        w.x = lds[4 * c + 0][b];
        w.y = lds[4 * c + 1][b];
        w.z = lds[4 * c + 2][b];
        w.w = lds[4 * c + 3][b];
        nt_store_f4(&out[(size_t)b * NNODE + n0 + 4 * c], w);
    }
}

extern "C" void kernel_launch(void* const* d_in, const int* in_sizes, int n_in,
                              void* d_out, int out_size, void* d_ws, size_t ws_size,
                              hipStream_t stream) {
    const float* x = (const float*)d_in[0];
    // Application order: edges3 (layer 0) ... edges0 (layer 3)
    const int* p0 = (const int*)d_in[4];
    const int* p1 = (const int*)d_in[3];
    const int* p2 = (const int*)d_in[2];
    const int* p3 = (const int*)d_in[1];

    // Two bf16 (N,B) buffers in d_ws: 128 MB each
    unsigned short* WS0 = (unsigned short*)d_ws;
    unsigned short* WS1 = WS0 + (size_t)NNODE * BATCH;
    float* OUT = (float*)d_out;

    // Per-layer CSR
    zero_counts_k<<<NLAYER * NNODE / 1024, 1024, 0, stream>>>();
    hist_k<<<NLAYER * NEDGE / 1024, 1024, 0, stream>>>(p0, p1, p2, p3);
    scan_block_k<<<NLAYER * SCAN_NBLK, SCAN_BLK, 0, stream>>>();
    scan_bsums_k<<<NLAYER, SCAN_NBLK, 0, stream>>>();
    scan_add_k<<<NLAYER * SCAN_NBLK, SCAN_BLK, 0, stream>>>();
    fill_k<<<NLAYER * NEDGE / 1024, 1024, 0, stream>>>(p0, p1, p2, p3);

    // Pair-combined CSR (2 pairs)
    count_pair_k<<<2 * NNODE / 1024, 1024, 0, stream>>>();
    pscan_block_k<<<2 * SCAN_NBLK, SCAN_BLK, 0, stream>>>();
    pscan_bsums_k<<<2, SCAN_NBLK, 0, stream>>>();
    pscan_add_k<<<2 * SCAN_NBLK, SCAN_BLK, 0, stream>>>();
    fill_pair_k<<<2 * NNODE / 256, 256, 0, stream>>>();

    // x (B,N) f32 -> WS0 (N,B) bf16 (cached stores: sweep0 reads it next)
    transpose_bf_k<<<dim3(NNODE / 64, BATCH / 64), dim3(16, 16), 0, stream>>>(x, WS0);

    // sweep 0 (pair 0): WS0 -> WS1 (bf16, full-line NT)
    gather_p_k<<<NNODE / 8, 512, 0, stream>>>((const uint4*)WS0, (uint4*)WS1, 0);
    // sweep 1 (pair 1) fused with transpose-back: WS1 (N,B) bf16 -> d_out (B,N) f32 (full-line NT)
    gather_tr_p_k<<<NNODE / 16, 1024, 0, stream>>>((const uint4*)WS1, OUT, 1);
}